// Round 1
// baseline (226.240 us; speedup 1.0000x reference)
//
#include <hip/hip_runtime.h>

#define D 128
#define K 64

typedef __attribute__((ext_vector_type(8))) short short8;   // 8 bf16 in 4 VGPRs
typedef __attribute__((ext_vector_type(4))) float f32x4;

// round-to-nearest-even float -> bf16 bits (inputs are finite, no NaN handling needed)
__device__ inline short f2bf(float f) {
  union { float f; unsigned u; } v; v.f = f;
  unsigned u = v.u;
  return (short)((u + 0x7fffu + ((u >> 16) & 1u)) >> 16);
}

// DPP row_ror allreduce helpers. DPP "rows" are 16 lanes on CDNA = exactly our
// lid-group (lane&15 within each quad). Rotate-based butterfly: after ror
// 1,2,4,8 every lane holds the full 16-lane reduction. Pure VALU - no DS pipe,
// no lgkmcnt wait chains (replaces 48 ds_swizzle per tile).
template<int CTRL>
__device__ inline float dpp_ror(float x) {
  return __builtin_bit_cast(float, __builtin_amdgcn_update_dpp(
      0, __builtin_bit_cast(int, x), CTRL, 0xF, 0xF, true));
}
__device__ inline float rowsum16(float v) {
  v += dpp_ror<0x121>(v);   // row_ror:1
  v += dpp_ror<0x122>(v);   // row_ror:2
  v += dpp_ror<0x124>(v);   // row_ror:4
  v += dpp_ror<0x128>(v);   // row_ror:8
  return v;
}
__device__ inline float rowmax16(float v) {
  v = fmaxf(v, dpp_ror<0x121>(v));
  v = fmaxf(v, dpp_ror<0x122>(v));
  v = fmaxf(v, dpp_ror<0x124>(v));
  v = fmaxf(v, dpp_ror<0x128>(v));
  return v;
}

// ws layout (floats): [0..16) accumulator slots; [16..80) mnorm[64]; [128..) bf16(2*m) as 8192 shorts
__global__ void prep_kernel(const float* __restrict__ m, float* ws) {
  int tid = threadIdx.x;
  if (tid < 16) ws[tid] = 0.0f;
  if (tid < K) {
    const float* mr = m + tid * D;
    float s = 0.f;
    for (int d = 0; d < D; ++d) s += mr[d] * mr[d];
    ws[16 + tid] = s;
  }
  short* mb = (short*)(ws + 128);
  for (int i = tid; i < K * D; i += blockDim.x) mb[i] = f2bf(2.0f * m[i]);
}

__launch_bounds__(256, 4)   // cap VGPR<=128: >=4 waves/SIMD resident
__global__ void main_kernel(const float* __restrict__ x, float* ws, int nTiles, int totalWaves) {
  // B fragments (2*m bf16) live in LDS, not registers: frees 64 persistent VGPRs.
  // Swizzle: 16B chunk at linear index i stored at i ^ ((i>>4)&7) (row = i>>4,
  // XOR row&7 into the chunk-within-row bits) -> ds_read_b128 of 16 different
  // rows at the same column spreads uniformly over all 32 banks.
  __shared__ short8 bsm[1024];  // 16 KB
  const float* mnorm = ws + 16;
  const short8* mbv = (const short8*)(ws + 128);
  for (int i = threadIdx.x; i < 1024; i += blockDim.x)
    bsm[i ^ ((i >> 4) & 7)] = mbv[i];
  __syncthreads();

  const int lane = threadIdx.x & 63;
  const int lid  = lane & 15;   // A: M row / B: N col / C/D: col (j)
  const int quad = lane >> 4;   // k-element group; C/D row = quad*4+reg

  float mn[4];
#pragma unroll
  for (int jt = 0; jt < 4; ++jt) mn[jt] = mnorm[jt * 16 + lid];

  // Per-kk swizzled LDS chunk index (jt adds a pure-immediate 256-chunk offset:
  // jt bits are above the XOR bits, so no carry interaction).
  int cbase[4];
#pragma unroll
  for (int kk = 0; kk < 4; ++kk)
    cbase[kk] = (lid * 16 + kk * 4 + quad) ^ (lid & 7);

  const int wave = blockIdx.x * (blockDim.x >> 6) + (threadIdx.x >> 6);
  const size_t laneOff = (size_t)lid * D + quad * 8;
  float hacc = 0.f;

  // Software pipeline: tile t's 8 dwordx4 loads are issued one iteration early,
  // so ~900cy HBM latency hides under the previous tile's MFMA + epilogue.
  f32x4 ld[8];
  {
    const float* xb = x + (size_t)wave * (16 * D) + laneOff;
#pragma unroll
    for (int kk = 0; kk < 4; ++kk) {
      ld[2 * kk]     = *(const f32x4*)(xb + kk * 32);
      ld[2 * kk + 1] = *(const f32x4*)(xb + kk * 32 + 4);
    }
  }

  for (int t = wave; t < nTiles; t += totalWaves) {
    // consume the in-flight loads into bf16 A fragments
    short8 a[4];
#pragma unroll
    for (int kk = 0; kk < 4; ++kk) {
      f32x4 v0 = ld[2 * kk], v1 = ld[2 * kk + 1];
      short8 av;
      av[0] = f2bf(v0[0]); av[1] = f2bf(v0[1]); av[2] = f2bf(v0[2]); av[3] = f2bf(v0[3]);
      av[4] = f2bf(v1[0]); av[5] = f2bf(v1[1]); av[6] = f2bf(v1[2]); av[7] = f2bf(v1[3]);
      a[kk] = av;
    }

    // prefetch next tile (registers just freed by the pack above)
    int tn = t + totalWaves;
    if (tn < nTiles) {
      const float* xb = x + (size_t)tn * (16 * D) + laneOff;
#pragma unroll
      for (int kk = 0; kk < 4; ++kk) {
        ld[2 * kk]     = *(const f32x4*)(xb + kk * 32);
        ld[2 * kk + 1] = *(const f32x4*)(xb + kk * 32 + 4);
      }
    }

    f32x4 acc[4];
#pragma unroll
    for (int jt = 0; jt < 4; ++jt) acc[jt] = (f32x4){0.f, 0.f, 0.f, 0.f};
#pragma unroll
    for (int kk = 0; kk < 4; ++kk)
#pragma unroll
      for (int jt = 0; jt < 4; ++jt) {
        short8 b = bsm[cbase[kk] + jt * 256];
        acc[jt] = __builtin_amdgcn_mfma_f32_16x16x32_bf16(a[kk], b, acc[jt], 0, 0, 0);
      }

    // Epilogue: row r (= tile row quad*4+r) has its 64 scores spread as
    // 4 jt-regs here x 16 lanes (lane&15). DPP row_ror allreduce over lid.
#pragma unroll
    for (int r = 0; r < 4; ++r) {
      float s0 = acc[0][r] - mn[0];
      float s1 = acc[1][r] - mn[1];
      float s2 = acc[2][r] - mn[2];
      float s3 = acc[3][r] - mn[3];
      float mx = rowmax16(fmaxf(fmaxf(s0, s1), fmaxf(s2, s3)));
      float t0 = s0 - mx, t1 = s1 - mx, t2 = s2 - mx, t3 = s3 - mx;
      float e0 = __expf(t0), e1 = __expf(t1), e2 = __expf(t2), e3 = __expf(t3);
      float S0 = rowsum16((e0 + e1) + (e2 + e3));
      float S1 = rowsum16((t0 * e0 + t1 * e1) + (t2 * e2 + t3 * e3));
      // H = ln(sum e^t) - sum(t e^t)/sum(e^t); uniform check: ln 64 OK
      float H = __logf(S0) - S1 / S0;
      if (lid == 0) hacc += H;  // one lane per quad-group owns rows quad*4+r
    }
  }

  // wave reduce then block reduce then one atomic per block
  for (int off = 1; off < 64; off <<= 1) hacc += __shfl_xor(hacc, off, 64);
  __shared__ float red[4];
  if (lane == 0) red[threadIdx.x >> 6] = hacc;
  __syncthreads();
  if (threadIdx.x == 0) atomicAdd(ws, red[0] + red[1] + red[2] + red[3]);
}

__global__ void final_kernel(const float* __restrict__ m, const float* ws, float* out, int nRows) {
  __shared__ float mu[D];
  int lane = threadIdx.x;  // 64 threads
  for (int d = lane; d < D; d += 64) {
    float s = 0.f;
    for (int j = 0; j < K; ++j) s += m[j * D + d];
    mu[d] = s * (1.0f / K);
  }
  __syncthreads();
  const float* mr = m + lane * D;
  float dot = 0.f;
  for (int d = 0; d < D; ++d) dot += mu[d] * mr[d];
  float s = 2.f * dot - ws[16 + lane];  // shift-invariant: drop ||mu||^2
  float mx = s;
  for (int off = 1; off < 64; off <<= 1) mx = fmaxf(mx, __shfl_xor(mx, off, 64));
  float t = s - mx;
  float e = __expf(t);
  float S0 = e, S1 = t * e;
  for (int off = 1; off < 64; off <<= 1) {
    S0 += __shfl_xor(S0, off, 64);
    S1 += __shfl_xor(S1, off, 64);
  }
  float inter = __logf(S0) - S1 / S0;
  if (lane == 0) {
    float intra = ws[0] / (float)nRows;
    out[0] = intra - inter;  // LAMB = 1
    out[1] = intra;
    out[2] = inter;
  }
}

extern "C" void kernel_launch(void* const* d_in, const int* in_sizes, int n_in,
                              void* d_out, int out_size, void* d_ws, size_t ws_size,
                              hipStream_t stream) {
  const float* x = (const float*)d_in[0];
  const float* m = (const float*)d_in[1];
  float* ws = (float*)d_ws;
  float* out = (float*)d_out;
  const int N = in_sizes[0] / D;   // 262144
  const int nTiles = N / 16;       // 16384

  prep_kernel<<<1, 256, 0, stream>>>(m, ws);

  const int blocks = 1024;                  // 4 blocks/CU, 16 waves/CU
  const int totalWaves = blocks * 4;        // 4 tiles per wave, exact (16384/4096)
  main_kernel<<<blocks, 256, 0, stream>>>(x, ws, nTiles, totalWaves);

  final_kernel<<<1, 64, 0, stream>>>(m, ws, out, N);
}

// Round 2
// 215.233 us; speedup vs baseline: 1.0511x; 1.0511x over previous
//
#include <hip/hip_runtime.h>

#define D 128
#define K 64

typedef __attribute__((ext_vector_type(8))) short short8;   // 8 bf16 in 4 VGPRs
typedef __attribute__((ext_vector_type(4))) short bf4;      // 4 bf16 in 2 VGPRs
typedef __attribute__((ext_vector_type(4))) float f32x4;

// round-to-nearest-even float -> bf16 bits (inputs are finite, no NaN handling needed)
__device__ inline short f2bf(float f) {
  union { float f; unsigned u; } v; v.f = f;
  unsigned u = v.u;
  return (short)((u + 0x7fffu + ((u >> 16) & 1u)) >> 16);
}

// DPP row_ror allreduce helpers (16-lane rows = our lid groups). Pure VALU.
template<int CTRL>
__device__ inline float dpp_ror(float x) {
  return __builtin_bit_cast(float, __builtin_amdgcn_update_dpp(
      0, __builtin_bit_cast(int, x), CTRL, 0xF, 0xF, true));
}
__device__ inline float rowsum16(float v) {
  v += dpp_ror<0x121>(v);
  v += dpp_ror<0x122>(v);
  v += dpp_ror<0x124>(v);
  v += dpp_ror<0x128>(v);
  return v;
}
__device__ inline float rowmax16(float v) {
  v = fmaxf(v, dpp_ror<0x121>(v));
  v = fmaxf(v, dpp_ror<0x122>(v));
  v = fmaxf(v, dpp_ror<0x124>(v));
  v = fmaxf(v, dpp_ror<0x128>(v));
  return v;
}

// ws layout (floats): [0..16) accumulator slots; [16..80) mnorm[64]; [128..) bf16(2*m) as 8192 shorts
__global__ void prep_kernel(const float* __restrict__ m, float* ws) {
  int tid = threadIdx.x;
  if (tid < 16) ws[tid] = 0.0f;
  if (tid < K) {
    const float* mr = m + tid * D;
    float s = 0.f;
    for (int d = 0; d < D; ++d) s += mr[d] * mr[d];
    ws[16 + tid] = s;
  }
  short* mb = (short*)(ws + 128);
  for (int i = tid; i < K * D; i += blockDim.x) mb[i] = f2bf(2.0f * m[i]);
}

__launch_bounds__(256, 4)
__global__ void main_kernel(const float* __restrict__ x, float* ws, int nTiles, int totalWaves) {
  // B (2*m bf16) in LDS, chunk-swizzled (read pattern verified ~conflict-free).
  __shared__ short8 bsm[1024];          // 16 KB
  // Per-wave A staging tile: 16 rows x 128 bf16 = 4 KB, row-XOR chunk swizzle.
  // Each wave owns its region -> no barriers, only wave-local lgkm ordering.
  __shared__ char asmem[4][4096];       // 16 KB

  const float* mnorm = ws + 16;
  const short8* mbv = (const short8*)(ws + 128);
  for (int i = threadIdx.x; i < 1024; i += blockDim.x)
    bsm[i ^ ((i >> 4) & 7)] = mbv[i];
  __syncthreads();

  const int lane = threadIdx.x & 63;
  const int lid  = lane & 15;   // A row / B col / C-D col (j)
  const int quad = lane >> 4;   // k-element group; C/D row = quad*4+reg
  const int wid  = threadIdx.x >> 6;
  char* amem = asmem[wid];

  float mn[4];
#pragma unroll
  for (int jt = 0; jt < 4; ++jt) mn[jt] = mnorm[jt * 16 + lid];

  // B chunk indices (swizzled)
  int cbase[4];
#pragma unroll
  for (int kk = 0; kk < 4; ++kk)
    cbase[kk] = (lid * 16 + kk * 4 + quad) ^ (lid & 7);

  // A-stage write constants: coalesced load p gives lane i floats p*256+i*4..+3
  //   row r = 2p + (i>>5), chunk c = (i&31)>>1, half h = i&1
  //   stored at r*256 + ((c ^ r)<<4) + h*8   (XOR spreads banks on the read)
  const int hi = lane >> 5;
  const int wc = (lane & 31) >> 1;
  const int wh = lane & 1;

  // A-fragment read: lane (lid,quad), kk -> row lid, chunk kk*4+quad (^lid)
  int ra[4];
#pragma unroll
  for (int kk = 0; kk < 4; ++kk)
    ra[kk] = lid * 256 + ((((kk << 2) | quad) ^ lid) << 4);

  const int wave = blockIdx.x * (blockDim.x >> 6) + wid;
  float hacc = 0.f;

  // Fully-coalesced x loads: instruction p reads 1 KB contiguous (lane*16B).
  f32x4 ld[8];
  {
    const float* xb = x + (size_t)wave * (16 * D) + lane * 4;
#pragma unroll
    for (int p = 0; p < 8; ++p) ld[p] = *(const f32x4*)(xb + p * 256);
  }

  for (int t = wave; t < nTiles; t += totalWaves) {
    // pack f32->bf16 and stage into the wave's LDS tile (ds_write_b64 x8)
#pragma unroll
    for (int p = 0; p < 8; ++p) {
      f32x4 v = ld[p];
      bf4 s;
      s[0] = f2bf(v[0]); s[1] = f2bf(v[1]); s[2] = f2bf(v[2]); s[3] = f2bf(v[3]);
      int r = 2 * p + hi;
      *(bf4*)(amem + r * 256 + ((wc ^ r) << 4) + wh * 8) = s;
    }

    // prefetch next tile into the register double-buffer (coalesced)
    int tn = t + totalWaves;
    if (tn < nTiles) {
      const float* xb = x + (size_t)tn * (16 * D) + lane * 4;
#pragma unroll
      for (int p = 0; p < 8; ++p) ld[p] = *(const f32x4*)(xb + p * 256);
    }

    // read A fragments back in MFMA layout (ds_read_b128 x4, swizzled)
    short8 a[4];
#pragma unroll
    for (int kk = 0; kk < 4; ++kk)
      a[kk] = *(const short8*)(amem + ra[kk]);

    f32x4 acc[4];
#pragma unroll
    for (int jt = 0; jt < 4; ++jt) acc[jt] = (f32x4){0.f, 0.f, 0.f, 0.f};
#pragma unroll
    for (int kk = 0; kk < 4; ++kk)
#pragma unroll
      for (int jt = 0; jt < 4; ++jt) {
        short8 b = bsm[cbase[kk] + jt * 256];
        acc[jt] = __builtin_amdgcn_mfma_f32_16x16x32_bf16(a[kk], b, acc[jt], 0, 0, 0);
      }

    // Epilogue: row r (= tile row quad*4+r) has 64 scores spread as 4 jt-regs
    // x 16 lanes. DPP row allreduce over lid.
#pragma unroll
    for (int r = 0; r < 4; ++r) {
      float s0 = acc[0][r] - mn[0];
      float s1 = acc[1][r] - mn[1];
      float s2 = acc[2][r] - mn[2];
      float s3 = acc[3][r] - mn[3];
      float mx = rowmax16(fmaxf(fmaxf(s0, s1), fmaxf(s2, s3)));
      float t0 = s0 - mx, t1 = s1 - mx, t2 = s2 - mx, t3 = s3 - mx;
      float e0 = __expf(t0), e1 = __expf(t1), e2 = __expf(t2), e3 = __expf(t3);
      float S0 = rowsum16((e0 + e1) + (e2 + e3));
      float S1 = rowsum16((t0 * e0 + t1 * e1) + (t2 * e2 + t3 * e3));
      float H = __logf(S0) - S1 / S0;
      if (lid == 0) hacc += H;  // one lane per quad-group owns rows quad*4+r
    }
  }

  // wave reduce then block reduce then one atomic per block
  for (int off = 1; off < 64; off <<= 1) hacc += __shfl_xor(hacc, off, 64);
  __shared__ float red[4];
  if (lane == 0) red[wid] = hacc;
  __syncthreads();
  if (threadIdx.x == 0) atomicAdd(ws, red[0] + red[1] + red[2] + red[3]);
}

__global__ void final_kernel(const float* __restrict__ m, const float* ws, float* out, int nRows) {
  __shared__ float mu[D];
  int lane = threadIdx.x;  // 64 threads
  for (int d = lane; d < D; d += 64) {
    float s = 0.f;
    for (int j = 0; j < K; ++j) s += m[j * D + d];
    mu[d] = s * (1.0f / K);
  }
  __syncthreads();
  const float* mr = m + lane * D;
  float dot = 0.f;
  for (int d = 0; d < D; ++d) dot += mu[d] * mr[d];
  float s = 2.f * dot - ws[16 + lane];  // shift-invariant: drop ||mu||^2
  float mx = s;
  for (int off = 1; off < 64; off <<= 1) mx = fmaxf(mx, __shfl_xor(mx, off, 64));
  float t = s - mx;
  float e = __expf(t);
  float S0 = e, S1 = t * e;
  for (int off = 1; off < 64; off <<= 1) {
    S0 += __shfl_xor(S0, off, 64);
    S1 += __shfl_xor(S1, off, 64);
  }
  float inter = __logf(S0) - S1 / S0;
  if (lane == 0) {
    float intra = ws[0] / (float)nRows;
    out[0] = intra - inter;  // LAMB = 1
    out[1] = intra;
    out[2] = inter;
  }
}

extern "C" void kernel_launch(void* const* d_in, const int* in_sizes, int n_in,
                              void* d_out, int out_size, void* d_ws, size_t ws_size,
                              hipStream_t stream) {
  const float* x = (const float*)d_in[0];
  const float* m = (const float*)d_in[1];
  float* ws = (float*)d_ws;
  float* out = (float*)d_out;
  const int N = in_sizes[0] / D;   // 262144
  const int nTiles = N / 16;       // 16384

  prep_kernel<<<1, 256, 0, stream>>>(m, ws);

  const int blocks = 1024;                  // 4 blocks/CU, 16 waves/CU
  const int totalWaves = blocks * 4;        // 4 tiles per wave, exact (16384/4096)
  main_kernel<<<blocks, 256, 0, stream>>>(x, ws, nTiles, totalWaves);

  final_kernel<<<1, 64, 0, stream>>>(m, ws, out, N);
}

// Round 3
// 214.085 us; speedup vs baseline: 1.0568x; 1.0054x over previous
//
#include <hip/hip_runtime.h>

#define D 128
#define K 64
#define BLOCK_WAVES 8

typedef __attribute__((ext_vector_type(8))) short short8;   // 8 bf16 in 4 VGPRs
typedef __attribute__((ext_vector_type(2))) int int2v;      // 4 bf16 in 2 VGPRs
typedef __attribute__((ext_vector_type(4))) float f32x4;

// round-to-nearest-even float -> bf16 bits (prep kernel only)
__device__ inline short f2bf(float f) {
  union { float f; unsigned u; } v; v.f = f;
  unsigned u = v.u;
  return (short)((u + 0x7fffu + ((u >> 16) & 1u)) >> 16);
}

// HW packed f32x2 -> bf16x2 convert (RNE, same as f2bf for finite inputs).
// One instruction replaces ~8 integer ops. No builtin on gfx950 (T12) -> asm.
__device__ inline int cvt_pk_bf16(float lo, float hi) {
  int r;
  asm("v_cvt_pk_bf16_f32 %0, %1, %2" : "=v"(r) : "v"(lo), "v"(hi));
  return r;
}

// DPP row_ror allreduce helpers (16-lane rows = our lid groups). Pure VALU.
template<int CTRL>
__device__ inline float dpp_ror(float x) {
  return __builtin_bit_cast(float, __builtin_amdgcn_update_dpp(
      0, __builtin_bit_cast(int, x), CTRL, 0xF, 0xF, true));
}
__device__ inline float rowsum16(float v) {
  v += dpp_ror<0x121>(v);
  v += dpp_ror<0x122>(v);
  v += dpp_ror<0x124>(v);
  v += dpp_ror<0x128>(v);
  return v;
}
__device__ inline float rowmax16(float v) {
  v = fmaxf(v, dpp_ror<0x121>(v));
  v = fmaxf(v, dpp_ror<0x122>(v));
  v = fmaxf(v, dpp_ror<0x124>(v));
  v = fmaxf(v, dpp_ror<0x128>(v));
  return v;
}

// ws layout (floats): [0..16) accumulator slots; [16..80) mnorm[64]; [128..) bf16(2*m) as 8192 shorts
__global__ void prep_kernel(const float* __restrict__ m, float* ws) {
  int tid = threadIdx.x;
  if (tid < 16) ws[tid] = 0.0f;
  if (tid < K) {
    const float* mr = m + tid * D;
    float s = 0.f;
    for (int d = 0; d < D; ++d) s += mr[d] * mr[d];
    ws[16 + tid] = s;
  }
  short* mb = (short*)(ws + 128);
  for (int i = tid; i < K * D; i += blockDim.x) mb[i] = f2bf(2.0f * m[i]);
}

// 512 threads (8 waves) per block. LDS = 16KB bsm + 8*4KB stage ~= 48KB
// -> 3 blocks/CU = 24 waves/CU = 6 waves/SIMD (was 4). Latency hiding is the
// bottleneck: every pipe <30% busy at 4 waves/SIMD across 3 prior variants.
__launch_bounds__(512, 6)
__global__ void main_kernel(const float* __restrict__ x, float* ws, int nTiles, int totalWaves) {
  // B (2*m bf16) in LDS, chunk-swizzled.
  __shared__ short8 bsm[1024];                 // 16 KB, shared by all 8 waves
  // Per-wave A staging tile: 16 rows x 128 bf16 = 4 KB, row-XOR chunk swizzle.
  __shared__ char asmem[BLOCK_WAVES][4096];    // 32 KB

  const float* mnorm = ws + 16;
  const short8* mbv = (const short8*)(ws + 128);
  for (int i = threadIdx.x; i < 1024; i += blockDim.x)
    bsm[i ^ ((i >> 4) & 7)] = mbv[i];
  __syncthreads();

  const int lane = threadIdx.x & 63;
  const int lid  = lane & 15;   // A row / B col / C-D col (j)
  const int quad = lane >> 4;   // k-element group; C/D row = quad*4+reg
  const int wid  = threadIdx.x >> 6;
  char* amem = asmem[wid];

  float mn[4];
#pragma unroll
  for (int jt = 0; jt < 4; ++jt) mn[jt] = mnorm[jt * 16 + lid];

  // B chunk indices (swizzled)
  int cbase[4];
#pragma unroll
  for (int kk = 0; kk < 4; ++kk)
    cbase[kk] = (lid * 16 + kk * 4 + quad) ^ (lid & 7);

  // A-stage write constants: coalesced load p gives lane i floats p*256+i*4..+3
  //   row r = 2p + (i>>5), chunk c = (i&31)>>1, half h = i&1
  //   stored at r*256 + ((c ^ r)<<4) + h*8   (XOR spreads banks on the read)
  const int hi = lane >> 5;
  const int wc = (lane & 31) >> 1;
  const int wh = lane & 1;

  // A-fragment read: lane (lid,quad), kk -> row lid, chunk kk*4+quad (^lid)
  int ra[4];
#pragma unroll
  for (int kk = 0; kk < 4; ++kk)
    ra[kk] = lid * 256 + ((((kk << 2) | quad) ^ lid) << 4);

  const int wave = blockIdx.x * (blockDim.x >> 6) + wid;
  float hacc = 0.f;

  // Fully-coalesced x loads: instruction p reads 1 KB contiguous (lane*16B).
  f32x4 ld[8];
  if (wave < nTiles) {
    const float* xb = x + (size_t)wave * (16 * D) + lane * 4;
#pragma unroll
    for (int p = 0; p < 8; ++p) ld[p] = *(const f32x4*)(xb + p * 256);
  }

  for (int t = wave; t < nTiles; t += totalWaves) {
    // pack f32->bf16 (one v_cvt_pk_bf16_f32 per pair) and stage to LDS
#pragma unroll
    for (int p = 0; p < 8; ++p) {
      f32x4 v = ld[p];
      int2v s;
      s[0] = cvt_pk_bf16(v[0], v[1]);
      s[1] = cvt_pk_bf16(v[2], v[3]);
      int r = 2 * p + hi;
      *(int2v*)(amem + r * 256 + ((wc ^ r) << 4) + wh * 8) = s;
    }

    // prefetch next tile into the register buffer (coalesced)
    int tn = t + totalWaves;
    if (tn < nTiles) {
      const float* xb = x + (size_t)tn * (16 * D) + lane * 4;
#pragma unroll
      for (int p = 0; p < 8; ++p) ld[p] = *(const f32x4*)(xb + p * 256);
    }

    // read A fragments back in MFMA layout (ds_read_b128 x4, swizzled)
    short8 a[4];
#pragma unroll
    for (int kk = 0; kk < 4; ++kk)
      a[kk] = *(const short8*)(amem + ra[kk]);

    f32x4 acc[4];
#pragma unroll
    for (int jt = 0; jt < 4; ++jt) acc[jt] = (f32x4){0.f, 0.f, 0.f, 0.f};
#pragma unroll
    for (int kk = 0; kk < 4; ++kk)
#pragma unroll
      for (int jt = 0; jt < 4; ++jt) {
        short8 b = bsm[cbase[kk] + jt * 256];
        acc[jt] = __builtin_amdgcn_mfma_f32_16x16x32_bf16(a[kk], b, acc[jt], 0, 0, 0);
      }

    // Epilogue: row r (= tile row quad*4+r) has 64 scores spread as 4 jt-regs
    // x 16 lanes. DPP row allreduce over lid. The 4 rows are independent
    // chains the compiler can interleave.
#pragma unroll
    for (int r = 0; r < 4; ++r) {
      float s0 = acc[0][r] - mn[0];
      float s1 = acc[1][r] - mn[1];
      float s2 = acc[2][r] - mn[2];
      float s3 = acc[3][r] - mn[3];
      float mx = rowmax16(fmaxf(fmaxf(s0, s1), fmaxf(s2, s3)));
      float t0 = s0 - mx, t1 = s1 - mx, t2 = s2 - mx, t3 = s3 - mx;
      float e0 = __expf(t0), e1 = __expf(t1), e2 = __expf(t2), e3 = __expf(t3);
      float S0 = rowsum16((e0 + e1) + (e2 + e3));
      float S1 = rowsum16((t0 * e0 + t1 * e1) + (t2 * e2 + t3 * e3));
      float H = __logf(S0) - S1 / S0;
      if (lid == 0) hacc += H;  // one lane per quad-group owns rows quad*4+r
    }
  }

  // wave reduce then block reduce then one atomic per block
  for (int off = 1; off < 64; off <<= 1) hacc += __shfl_xor(hacc, off, 64);
  __shared__ float red[BLOCK_WAVES];
  if (lane == 0) red[wid] = hacc;
  __syncthreads();
  if (threadIdx.x == 0) {
    float s = 0.f;
#pragma unroll
    for (int w = 0; w < BLOCK_WAVES; ++w) s += red[w];
    atomicAdd(ws, s);
  }
}

__global__ void final_kernel(const float* __restrict__ m, const float* ws, float* out, int nRows) {
  __shared__ float mu[D];
  int lane = threadIdx.x;  // 64 threads
  for (int d = lane; d < D; d += 64) {
    float s = 0.f;
    for (int j = 0; j < K; ++j) s += m[j * D + d];
    mu[d] = s * (1.0f / K);
  }
  __syncthreads();
  const float* mr = m + lane * D;
  float dot = 0.f;
  for (int d = 0; d < D; ++d) dot += mu[d] * mr[d];
  float s = 2.f * dot - ws[16 + lane];  // shift-invariant: drop ||mu||^2
  float mx = s;
  for (int off = 1; off < 64; off <<= 1) mx = fmaxf(mx, __shfl_xor(mx, off, 64));
  float t = s - mx;
  float e = __expf(t);
  float S0 = e, S1 = t * e;
  for (int off = 1; off < 64; off <<= 1) {
    S0 += __shfl_xor(S0, off, 64);
    S1 += __shfl_xor(S1, off, 64);
  }
  float inter = __logf(S0) - S1 / S0;
  if (lane == 0) {
    float intra = ws[0] / (float)nRows;
    out[0] = intra - inter;  // LAMB = 1
    out[1] = intra;
    out[2] = inter;
  }
}

extern "C" void kernel_launch(void* const* d_in, const int* in_sizes, int n_in,
                              void* d_out, int out_size, void* d_ws, size_t ws_size,
                              hipStream_t stream) {
  const float* x = (const float*)d_in[0];
  const float* m = (const float*)d_in[1];
  float* ws = (float*)d_ws;
  float* out = (float*)d_out;
  const int N = in_sizes[0] / D;   // 262144
  const int nTiles = N / 16;       // 16384

  prep_kernel<<<1, 256, 0, stream>>>(m, ws);

  const int blocks = 768;                       // 3 blocks/CU (48KB LDS each)
  const int totalWaves = blocks * BLOCK_WAVES;  // 6144 waves, 2-3 tiles each
  main_kernel<<<blocks, 512, 0, stream>>>(x, ws, nTiles, totalWaves);

  final_kernel<<<1, 64, 0, stream>>>(m, ws, out, N);
}

// Round 4
// 204.837 us; speedup vs baseline: 1.1045x; 1.0451x over previous
//
#include <hip/hip_runtime.h>

#define D 128
#define K 64

typedef __attribute__((ext_vector_type(8))) short short8;   // 8 bf16 in 4 VGPRs
typedef __attribute__((ext_vector_type(2))) int int2v;      // 4 bf16 in 2 VGPRs
typedef __attribute__((ext_vector_type(4))) float f32x4;

// round-to-nearest-even float -> bf16 bits (finite inputs)
__device__ inline short f2bf(float f) {
  union { float f; unsigned u; } v; v.f = f;
  unsigned u = v.u;
  return (short)((u + 0x7fffu + ((u >> 16) & 1u)) >> 16);
}

// HW packed f32x2 -> bf16x2 (RNE, matches f2bf). No builtin on gfx950 -> asm.
__device__ inline int cvt_pk_bf16(float lo, float hi) {
  int r;
  asm("v_cvt_pk_bf16_f32 %0, %1, %2" : "=v"(r) : "v"(lo), "v"(hi));
  return r;
}

// DPP row_ror allreduce (16-lane rows = lid groups). Pure VALU, no DS pipe.
template<int CTRL>
__device__ inline float dpp_ror(float x) {
  return __builtin_bit_cast(float, __builtin_amdgcn_update_dpp(
      0, __builtin_bit_cast(int, x), CTRL, 0xF, 0xF, true));
}
__device__ inline float rowsum16(float v) {
  v += dpp_ror<0x121>(v);
  v += dpp_ror<0x122>(v);
  v += dpp_ror<0x124>(v);
  v += dpp_ror<0x128>(v);
  return v;
}
__device__ inline float rowmax16(float v) {
  v = fmaxf(v, dpp_ror<0x121>(v));
  v = fmaxf(v, dpp_ror<0x122>(v));
  v = fmaxf(v, dpp_ror<0x124>(v));
  v = fmaxf(v, dpp_ror<0x128>(v));
  return v;
}

// Load tile t's 16x128 f32 rows, fully coalesced: inst p reads 1 KB contiguous.
#define LOADX(dst, t) do {                                                  \
    const f32x4* xb = (const f32x4*)(x + (size_t)(t) * (16 * D)) + lane;    \
    _Pragma("unroll") for (int p = 0; p < 8; ++p) dst[p] = xb[p * 64];      \
  } while (0)

// Pack f32->bf16 and stage into this wave's LDS tile (row-XOR chunk swizzle).
#define PACKX(src) do {                                                     \
    _Pragma("unroll") for (int p = 0; p < 8; ++p) {                         \
      f32x4 v = src[p];                                                     \
      int2v s;                                                              \
      s[0] = cvt_pk_bf16(v[0], v[1]);                                       \
      s[1] = cvt_pk_bf16(v[2], v[3]);                                       \
      int r = 2 * p + hi;                                                   \
      *(int2v*)(amem + r * 256 + ((wc ^ r) << 4) + wh * 8) = s;             \
    }                                                                       \
  } while (0)

// ds_read A fragments, 16 MFMA, online-entropy epilogue -> hacc.
#define TILE_COMPUTE() do {                                                 \
    f32x4 acc[4];                                                           \
    _Pragma("unroll") for (int jt = 0; jt < 4; ++jt)                        \
      acc[jt] = (f32x4){0.f, 0.f, 0.f, 0.f};                                \
    _Pragma("unroll") for (int kk = 0; kk < 4; ++kk) {                      \
      short8 afrag = *(const short8*)(amem + ra[kk]);                       \
      _Pragma("unroll") for (int jt = 0; jt < 4; ++jt)                      \
        acc[jt] = __builtin_amdgcn_mfma_f32_16x16x32_bf16(                  \
            afrag, bsm[cbase[kk] + jt * 256], acc[jt], 0, 0, 0);            \
    }                                                                       \
    _Pragma("unroll") for (int r = 0; r < 4; ++r) {                         \
      float s0 = acc[0][r] - mn[0];                                         \
      float s1 = acc[1][r] - mn[1];                                         \
      float s2 = acc[2][r] - mn[2];                                         \
      float s3 = acc[3][r] - mn[3];                                         \
      float mx = rowmax16(fmaxf(fmaxf(s0, s1), fmaxf(s2, s3)));             \
      float t0 = s0 - mx, t1 = s1 - mx, t2 = s2 - mx, t3 = s3 - mx;         \
      float e0 = __expf(t0), e1 = __expf(t1);                               \
      float e2 = __expf(t2), e3 = __expf(t3);                               \
      float S0 = rowsum16((e0 + e1) + (e2 + e3));                           \
      float S1 = rowsum16((t0 * e0 + t1 * e1) + (t2 * e2 + t3 * e3));       \
      float H = __logf(S0) - S1 / S0;                                       \
      hacc += (lid == 0) ? H : 0.0f;                                        \
    }                                                                       \
  } while (0)

// 256 threads (4 waves), 4 blocks/CU. Depth-2 register pipeline: two static
// load buffers, loop unrolled x2 so 8-16 KB of loads stay in flight per wave
// continuously (prior depth-1 exposed full HBM latency once per tile).
__launch_bounds__(256, 4)
__global__ void main_kernel(const float* __restrict__ x, const float* __restrict__ m,
                            float* ws, int nTiles, int totalWaves) {
  __shared__ short8 bsm[1024];        // 16 KB: bf16(2*m), chunk-swizzled
  __shared__ float mnorms[K];
  __shared__ char asmem[4][4096];     // per-wave A staging tiles

  const int tid = threadIdx.x;
  // Block-local prep (replaces the serial prep_kernel launch): m is 32 KB,
  // L2/L3-served after the first block per XCD.
  for (int i = tid; i < K * D; i += 256) {
    int c = i >> 3, e = i & 7;
    int cs = c ^ ((c >> 4) & 7);
    ((short*)bsm)[cs * 8 + e] = f2bf(2.0f * m[i]);
  }
  if (tid < K) {
    const float* mr = m + tid * D;
    float s = 0.f;
    for (int d = 0; d < D; ++d) s += mr[d] * mr[d];
    mnorms[tid] = s;
  }
  __syncthreads();

  const int lane = tid & 63;
  const int lid  = lane & 15;   // A row / B col / C-D col (j)
  const int quad = lane >> 4;   // k group; C/D row = quad*4+reg
  const int wid  = tid >> 6;
  char* amem = asmem[wid];

  float mn[4];
#pragma unroll
  for (int jt = 0; jt < 4; ++jt) mn[jt] = mnorms[jt * 16 + lid];

  int cbase[4], ra[4];
#pragma unroll
  for (int kk = 0; kk < 4; ++kk) {
    cbase[kk] = (lid * 16 + kk * 4 + quad) ^ (lid & 7);
    ra[kk] = lid * 256 + ((((kk << 2) | quad) ^ lid) << 4);
  }

  // A-stage write constants: load p gives lane i floats p*256 + i*4..+3
  //   row r = 2p + (i>>5), chunk c = (i&31)>>1, half h = i&1
  const int hi = lane >> 5;
  const int wc = (lane & 31) >> 1;
  const int wh = lane & 1;

  const int wave = blockIdx.x * 4 + wid;
  const int step = 2 * totalWaves;
  float hacc = 0.f;

  f32x4 ldA[8], ldB[8];
  int tA = wave, tB = wave + totalWaves;
  const int iters = nTiles / step;          // 2 for N=262144
  if (tA < nTiles) LOADX(ldA, tA);
  if (tB < nTiles) LOADX(ldB, tB);

  for (int it = 0; it < iters; ++it) {
    const bool more = (it + 1 < iters);
    // ---- tile tA: consume ldA, immediately refill it for t+step ----
    PACKX(ldA);
    if (more) LOADX(ldA, tA + step);
    TILE_COMPUTE();
    // ---- tile tB ----
    PACKX(ldB);
    if (more) LOADX(ldB, tB + step);
    TILE_COMPUTE();
    tA += step; tB += step;
  }
  // generic tail (dead for N=262144: 16384 tiles = 4096 waves x 4 exactly)
  for (int t = wave + iters * step; t < nTiles; t += totalWaves) {
    LOADX(ldA, t);
    PACKX(ldA);
    TILE_COMPUTE();
  }

  // wave reduce -> block reduce -> one atomic per block
  for (int off = 1; off < 64; off <<= 1) hacc += __shfl_xor(hacc, off, 64);
  __shared__ float red[4];
  if (lane == 0) red[wid] = hacc;
  __syncthreads();
  if (tid == 0) atomicAdd(ws, red[0] + red[1] + red[2] + red[3]);
}

__global__ void final_kernel(const float* __restrict__ m, const float* ws, float* out, int nRows) {
  __shared__ float mu[D];
  int lane = threadIdx.x;  // 64 threads
  for (int d = lane; d < D; d += 64) {
    float s = 0.f;
    for (int j = 0; j < K; ++j) s += m[j * D + d];
    mu[d] = s * (1.0f / K);
  }
  __syncthreads();
  const float* mr = m + lane * D;
  float dot = 0.f, nrm = 0.f;
  for (int d = 0; d < D; ++d) {
    dot += mu[d] * mr[d];
    nrm += mr[d] * mr[d];
  }
  float s = 2.f * dot - nrm;  // shift-invariant: drop ||mu||^2
  float mx = s;
  for (int off = 1; off < 64; off <<= 1) mx = fmaxf(mx, __shfl_xor(mx, off, 64));
  float t = s - mx;
  float e = __expf(t);
  float S0 = e, S1 = t * e;
  for (int off = 1; off < 64; off <<= 1) {
    S0 += __shfl_xor(S0, off, 64);
    S1 += __shfl_xor(S1, off, 64);
  }
  float inter = __logf(S0) - S1 / S0;
  if (lane == 0) {
    float intra = ws[0] / (float)nRows;
    out[0] = intra - inter;  // LAMB = 1
    out[1] = intra;
    out[2] = inter;
  }
}

extern "C" void kernel_launch(void* const* d_in, const int* in_sizes, int n_in,
                              void* d_out, int out_size, void* d_ws, size_t ws_size,
                              hipStream_t stream) {
  const float* x = (const float*)d_in[0];
  const float* m = (const float*)d_in[1];
  float* ws = (float*)d_ws;
  float* out = (float*)d_out;
  const int N = in_sizes[0] / D;   // 262144
  const int nTiles = N / 16;       // 16384

  hipMemsetAsync(ws, 0, 64, stream);   // accumulator zero (replaces prep launch)

  const int blocks = 1024;             // 4 blocks/CU, all resident
  const int totalWaves = blocks * 4;   // 4096 waves x exactly 4 tiles
  main_kernel<<<blocks, 256, 0, stream>>>(x, m, ws, nTiles, totalWaves);

  final_kernel<<<1, 64, 0, stream>>>(m, ws, out, N);
}

// Round 5
// 201.847 us; speedup vs baseline: 1.1208x; 1.0148x over previous
//
#include <hip/hip_runtime.h>

#define D 128
#define K 64

typedef __attribute__((ext_vector_type(8))) short short8;   // 8 bf16 in 4 VGPRs
typedef __attribute__((ext_vector_type(2))) int int2v;      // 4 bf16 in 2 VGPRs
typedef __attribute__((ext_vector_type(4))) float f32x4;

// round-to-nearest-even float -> bf16 bits (finite inputs)
__device__ inline short f2bf(float f) {
  union { float f; unsigned u; } v; v.f = f;
  unsigned u = v.u;
  return (short)((u + 0x7fffu + ((u >> 16) & 1u)) >> 16);
}

// HW packed f32x2 -> bf16x2 (RNE, matches f2bf). No builtin on gfx950 -> asm.
__device__ inline int cvt_pk_bf16(float lo, float hi) {
  int r;
  asm("v_cvt_pk_bf16_f32 %0, %1, %2" : "=v"(r) : "v"(lo), "v"(hi));
  return r;
}

// DPP row_ror allreduce (16-lane rows = lid groups). Pure VALU, no DS pipe.
template<int CTRL>
__device__ inline float dpp_ror(float x) {
  return __builtin_bit_cast(float, __builtin_amdgcn_update_dpp(
      0, __builtin_bit_cast(int, x), CTRL, 0xF, 0xF, true));
}
__device__ inline float rowsum16(float v) {
  v += dpp_ror<0x121>(v);
  v += dpp_ror<0x122>(v);
  v += dpp_ror<0x124>(v);
  v += dpp_ror<0x128>(v);
  return v;
}
__device__ inline float rowmax16(float v) {
  v = fmaxf(v, dpp_ror<0x121>(v));
  v = fmaxf(v, dpp_ror<0x122>(v));
  v = fmaxf(v, dpp_ror<0x124>(v));
  v = fmaxf(v, dpp_ror<0x128>(v));
  return v;
}

// Load tile t's 16x128 f32 rows, fully coalesced: inst p reads 1 KB contiguous.
#define LOADX(dst, t) do {                                                  \
    const f32x4* xb = (const f32x4*)(x + (size_t)(t) * (16 * D)) + lane;    \
    _Pragma("unroll") for (int p = 0; p < 8; ++p) dst[p] = xb[p * 64];      \
  } while (0)

// Pack f32->bf16 and stage into this wave's LDS tile (row-XOR chunk swizzle).
#define PACKX(src) do {                                                     \
    _Pragma("unroll") for (int p = 0; p < 8; ++p) {                         \
      f32x4 v = src[p];                                                     \
      int2v s;                                                              \
      s[0] = cvt_pk_bf16(v[0], v[1]);                                       \
      s[1] = cvt_pk_bf16(v[2], v[3]);                                       \
      int r = 2 * p + hi;                                                   \
      *(int2v*)(amem + r * 256 + ((wc ^ r) << 4) + wh * 8) = s;             \
    }                                                                       \
  } while (0)

// ds_read A fragments, 16 MFMA, online-entropy epilogue -> hacc.
#define TILE_COMPUTE() do {                                                 \
    f32x4 acc[4];                                                           \
    _Pragma("unroll") for (int jt = 0; jt < 4; ++jt)                        \
      acc[jt] = (f32x4){0.f, 0.f, 0.f, 0.f};                                \
    _Pragma("unroll") for (int kk = 0; kk < 4; ++kk) {                      \
      short8 afrag = *(const short8*)(amem + ra[kk]);                       \
      _Pragma("unroll") for (int jt = 0; jt < 4; ++jt)                      \
        acc[jt] = __builtin_amdgcn_mfma_f32_16x16x32_bf16(                  \
            afrag, bsm[cbase[kk] + jt * 256], acc[jt], 0, 0, 0);            \
    }                                                                       \
    _Pragma("unroll") for (int r = 0; r < 4; ++r) {                         \
      float s0 = acc[0][r] - mn[0];                                         \
      float s1 = acc[1][r] - mn[1];                                         \
      float s2 = acc[2][r] - mn[2];                                         \
      float s3 = acc[3][r] - mn[3];                                         \
      float mx = rowmax16(fmaxf(fmaxf(s0, s1), fmaxf(s2, s3)));             \
      float t0 = s0 - mx, t1 = s1 - mx, t2 = s2 - mx, t3 = s3 - mx;         \
      float e0 = __expf(t0), e1 = __expf(t1);                               \
      float e2 = __expf(t2), e3 = __expf(t3);                               \
      float S0 = rowsum16((e0 + e1) + (e2 + e3));                           \
      float S1 = rowsum16((t0 * e0 + t1 * e1) + (t2 * e2 + t3 * e3));       \
      float H = __logf(S0) - S1 / S0;                                       \
      hacc += (lid == 0) ? H : 0.0f;                                        \
    }                                                                       \
  } while (0)

// Depth-4 per-wave pipeline: ALL 4 tiles' loads (32 x dwordx4 = 32 KB/wave)
// issued at wave start, drained in order. One latency hill per wave instead
// of one per tile. 128 VGPR of buffers -> ~200 total -> 2 waves/SIMD; TLP loss
// is irrelevant (VALU demand ~16%); MLP per CU stays >=256 KB continuously.
__launch_bounds__(256, 2)
__global__ void main_kernel(const float* __restrict__ x, const float* __restrict__ m,
                            float* ws, int nTiles, int totalWaves) {
  __shared__ short8 bsm[1024];        // 16 KB: bf16(2*m), chunk-swizzled
  __shared__ float mnorms[K];
  __shared__ char asmem[4][4096];     // per-wave A staging tiles

  const int tid = threadIdx.x;
  // Block-local prep: m is 32 KB, L2/L3-served after the first blocks.
  for (int i = tid; i < K * D; i += 256) {
    int c = i >> 3, e = i & 7;
    int cs = c ^ ((c >> 4) & 7);
    ((short*)bsm)[cs * 8 + e] = f2bf(2.0f * m[i]);
  }
  if (tid < K) {
    const float* mr = m + tid * D;
    float s = 0.f;
    for (int d = 0; d < D; ++d) s += mr[d] * mr[d];
    mnorms[tid] = s;
  }
  __syncthreads();

  const int lane = tid & 63;
  const int lid  = lane & 15;   // A row / B col / C-D col (j)
  const int quad = lane >> 4;   // k group; C/D row = quad*4+reg
  const int wid  = tid >> 6;
  char* amem = asmem[wid];

  float mn[4];
#pragma unroll
  for (int jt = 0; jt < 4; ++jt) mn[jt] = mnorms[jt * 16 + lid];

  int cbase[4], ra[4];
#pragma unroll
  for (int kk = 0; kk < 4; ++kk) {
    cbase[kk] = (lid * 16 + kk * 4 + quad) ^ (lid & 7);
    ra[kk] = lid * 256 + ((((kk << 2) | quad) ^ lid) << 4);
  }

  // A-stage write constants: load p gives lane i floats p*256 + i*4..+3
  //   row r = 2p + (i>>5), chunk c = (i&31)>>1, half h = i&1
  const int hi = lane >> 5;
  const int wc = (lane & 31) >> 1;
  const int wh = lane & 1;

  const int wave = blockIdx.x * 4 + wid;
  float hacc = 0.f;

  // ---- issue everything up front ----
  f32x4 ld0[8], ld1[8], ld2[8], ld3[8];
  const int t0 = wave;
  const int t1 = wave + totalWaves;
  const int t2 = wave + 2 * totalWaves;
  const int t3 = wave + 3 * totalWaves;
  LOADX(ld0, t0);
  if (t1 < nTiles) LOADX(ld1, t1);
  if (t2 < nTiles) LOADX(ld2, t2);
  if (t3 < nTiles) LOADX(ld3, t3);

  // ---- drain in order (compiler emits stepping vmcnt(24/16/8/0)) ----
  PACKX(ld0); TILE_COMPUTE();
  if (t1 < nTiles) { PACKX(ld1); TILE_COMPUTE(); }
  if (t2 < nTiles) { PACKX(ld2); TILE_COMPUTE(); }
  if (t3 < nTiles) { PACKX(ld3); TILE_COMPUTE(); }

  // wave reduce -> block reduce -> one plain store per block (no atomic,
  // no ws pre-zero: ws[blockIdx.x] is overwritten before final reads it)
  for (int off = 1; off < 64; off <<= 1) hacc += __shfl_xor(hacc, off, 64);
  __shared__ float red[4];
  if (lane == 0) red[wid] = hacc;
  __syncthreads();
  if (tid == 0) ws[blockIdx.x] = red[0] + red[1] + red[2] + red[3];
}

__global__ void final_kernel(const float* __restrict__ m, const float* ws, float* out,
                             int nRows, int nBlocks) {
  __shared__ float mu[D];
  int lane = threadIdx.x;  // 64 threads
  for (int d = lane; d < D; d += 64) {
    float s = 0.f;
    for (int j = 0; j < K; ++j) s += m[j * D + d];
    mu[d] = s * (1.0f / K);
  }
  __syncthreads();

  // sum per-block partials of the intra entropy
  float part = 0.f;
  for (int i = lane; i < nBlocks; i += 64) part += ws[i];
  for (int off = 1; off < 64; off <<= 1) part += __shfl_xor(part, off, 64);

  const float* mr = m + lane * D;
  float dot = 0.f, nrm = 0.f;
  for (int d = 0; d < D; ++d) {
    dot += mu[d] * mr[d];
    nrm += mr[d] * mr[d];
  }
  float s = 2.f * dot - nrm;  // shift-invariant: drop ||mu||^2
  float mx = s;
  for (int off = 1; off < 64; off <<= 1) mx = fmaxf(mx, __shfl_xor(mx, off, 64));
  float t = s - mx;
  float e = __expf(t);
  float S0 = e, S1 = t * e;
  for (int off = 1; off < 64; off <<= 1) {
    S0 += __shfl_xor(S0, off, 64);
    S1 += __shfl_xor(S1, off, 64);
  }
  float inter = __logf(S0) - S1 / S0;
  if (lane == 0) {
    float intra = part / (float)nRows;
    out[0] = intra - inter;  // LAMB = 1
    out[1] = intra;
    out[2] = inter;
  }
}

extern "C" void kernel_launch(void* const* d_in, const int* in_sizes, int n_in,
                              void* d_out, int out_size, void* d_ws, size_t ws_size,
                              hipStream_t stream) {
  const float* x = (const float*)d_in[0];
  const float* m = (const float*)d_in[1];
  float* ws = (float*)d_ws;
  float* out = (float*)d_out;
  const int N = in_sizes[0] / D;   // 262144
  const int nTiles = N / 16;       // 16384

  const int blocks = 1024;             // 4096 waves x exactly 4 tiles
  const int totalWaves = blocks * 4;
  main_kernel<<<blocks, 256, 0, stream>>>(x, m, ws, nTiles, totalWaves);

  final_kernel<<<1, 64, 0, stream>>>(m, ws, out, N, blocks);
}

// Round 6
// 198.177 us; speedup vs baseline: 1.1416x; 1.0185x over previous
//
#include <hip/hip_runtime.h>

#define D 128
#define K 64

typedef __attribute__((ext_vector_type(8))) short short8;   // 8 bf16 in 4 VGPRs
typedef __attribute__((ext_vector_type(2))) int int2v;      // 4 bf16 in 2 VGPRs
typedef __attribute__((ext_vector_type(4))) float f32x4;

// HW packed f32x2 -> bf16x2 (RNE). No builtin on gfx950 -> asm.
__device__ inline int cvt_pk_bf16(float lo, float hi) {
  int r;
  asm("v_cvt_pk_bf16_f32 %0, %1, %2" : "=v"(r) : "v"(lo), "v"(hi));
  return r;
}

// DPP row_ror allreduce (16-lane rows = lid groups). Pure VALU, no DS pipe.
template<int CTRL>
__device__ inline float dpp_ror(float x) {
  return __builtin_bit_cast(float, __builtin_amdgcn_update_dpp(
      0, __builtin_bit_cast(int, x), CTRL, 0xF, 0xF, true));
}
__device__ inline float rowsum16(float v) {
  v += dpp_ror<0x121>(v);
  v += dpp_ror<0x122>(v);
  v += dpp_ror<0x124>(v);
  v += dpp_ror<0x128>(v);
  return v;
}
__device__ inline float rowmax16(float v) {
  v = fmaxf(v, dpp_ror<0x121>(v));
  v = fmaxf(v, dpp_ror<0x122>(v));
  v = fmaxf(v, dpp_ror<0x124>(v));
  v = fmaxf(v, dpp_ror<0x128>(v));
  return v;
}

// Load tile t's 16x128 f32 rows, fully coalesced: inst p reads 1 KB contiguous.
#define LOADX(dst, t) do {                                                  \
    const f32x4* xb = (const f32x4*)(x + (size_t)(t) * (16 * D)) + lane;    \
    _Pragma("unroll") for (int p = 0; p < 8; ++p) dst[p] = xb[p * 64];      \
  } while (0)

// Pack f32->bf16 and stage into this wave's LDS tile (row-XOR chunk swizzle).
#define PACKX(src) do {                                                     \
    _Pragma("unroll") for (int p = 0; p < 8; ++p) {                         \
      f32x4 v = src[p];                                                     \
      int2v s;                                                              \
      s[0] = cvt_pk_bf16(v[0], v[1]);                                       \
      s[1] = cvt_pk_bf16(v[2], v[3]);                                       \
      int r = 2 * p + hi;                                                   \
      *(int2v*)(amem + r * 256 + ((wc ^ r) << 4) + wh * 8) = s;             \
    }                                                                       \
  } while (0)

// ds_read A fragments, 16 MFMA, online-entropy epilogue -> hacc.
#define TILE_COMPUTE() do {                                                 \
    f32x4 acc[4];                                                           \
    _Pragma("unroll") for (int jt = 0; jt < 4; ++jt)                        \
      acc[jt] = (f32x4){0.f, 0.f, 0.f, 0.f};                                \
    _Pragma("unroll") for (int kk = 0; kk < 4; ++kk) {                      \
      short8 afrag = *(const short8*)(amem + ra[kk]);                       \
      _Pragma("unroll") for (int jt = 0; jt < 4; ++jt)                      \
        acc[jt] = __builtin_amdgcn_mfma_f32_16x16x32_bf16(                  \
            afrag, bsm[cbase[kk] + jt * 256], acc[jt], 0, 0, 0);            \
    }                                                                       \
    _Pragma("unroll") for (int r = 0; r < 4; ++r) {                         \
      float s0 = acc[0][r] - mn[0];                                         \
      float s1 = acc[1][r] - mn[1];                                         \
      float s2 = acc[2][r] - mn[2];                                         \
      float s3 = acc[3][r] - mn[3];                                         \
      float mx = rowmax16(fmaxf(fmaxf(s0, s1), fmaxf(s2, s3)));             \
      float t0 = s0 - mx, t1 = s1 - mx, t2 = s2 - mx, t3 = s3 - mx;         \
      float e0 = __expf(t0), e1 = __expf(t1);                               \
      float e2 = __expf(t2), e3 = __expf(t3);                               \
      float S0 = rowsum16((e0 + e1) + (e2 + e3));                           \
      float S1 = rowsum16((t0 * e0 + t1 * e1) + (t2 * e2 + t3 * e3));       \
      float H = __logf(S0) - S1 / S0;                                       \
      hacc += (lid == 0) ? H : 0.0f;                                        \
    }                                                                       \
  } while (0)

// Single-batch residency: 512 blocks x 256 thr = 2 blocks/CU, ALL resident at
// once (no second-batch ramp, half the prep instances). 8 tiles/wave with a
// rolling depth-4 pipeline: {pack(ldk); refill(ldk,+4W); compute} keeps 24
// loads (24 KB) in flight per wave continuously -- never drains to vmcnt(0)
// until the final 4 tiles.
__launch_bounds__(256, 2)
__global__ void main_kernel(const float* __restrict__ x, const float* __restrict__ m,
                            float* ws, int totalWaves) {
  __shared__ short8 bsm[1024];        // 16 KB: bf16(2*m), chunk-swizzled
  __shared__ float mnorms[K];
  __shared__ char asmem[4][4096];     // per-wave A staging tiles

  const int tid = threadIdx.x;

  // Block-local prep, vectorized (f32x4): 8 dwordx4 per thread for bsm,
  // 32 dwordx4 for the 64 mnorm threads. ~4x shorter serial preamble than
  // the scalar version.
  const f32x4* mv4 = (const f32x4*)m;
#pragma unroll
  for (int i0 = 0; i0 < (K * D) / 4; i0 += 256) {
    int i = i0 + tid;
    f32x4 v = mv4[i];
    int c = i >> 1, h = i & 1;          // 16B chunk / half within chunk
    int cs = c ^ ((c >> 4) & 7);        // row-XOR chunk swizzle
    int2v s;
    s[0] = cvt_pk_bf16(2.f * v[0], 2.f * v[1]);
    s[1] = cvt_pk_bf16(2.f * v[2], 2.f * v[3]);
    *(int2v*)((char*)bsm + cs * 16 + h * 8) = s;
  }
  if (tid < K) {
    const f32x4* mr = (const f32x4*)(m + tid * D);
    float s = 0.f;
#pragma unroll
    for (int i = 0; i < 32; ++i) {
      f32x4 v = mr[i];
      s += (v[0] * v[0] + v[1] * v[1]) + (v[2] * v[2] + v[3] * v[3]);
    }
    mnorms[tid] = s;
  }
  __syncthreads();

  const int lane = tid & 63;
  const int lid  = lane & 15;   // A row / B col / C-D col (j)
  const int quad = lane >> 4;   // k group; C/D row = quad*4+reg
  const int wid  = tid >> 6;
  char* amem = asmem[wid];

  float mn[4];
#pragma unroll
  for (int jt = 0; jt < 4; ++jt) mn[jt] = mnorms[jt * 16 + lid];

  int cbase[4], ra[4];
#pragma unroll
  for (int kk = 0; kk < 4; ++kk) {
    cbase[kk] = (lid * 16 + kk * 4 + quad) ^ (lid & 7);
    ra[kk] = lid * 256 + ((((kk << 2) | quad) ^ lid) << 4);
  }

  // A-stage write constants: load p gives lane i floats p*256 + i*4..+3
  //   row r = 2p + (i>>5), chunk c = (i&31)>>1, half h = i&1
  const int hi = lane >> 5;
  const int wc = (lane & 31) >> 1;
  const int wh = lane & 1;

  const int wave = blockIdx.x * 4 + wid;
  const int W = totalWaves;           // 2048: tiles wave + k*W, k = 0..7 exact
  float hacc = 0.f;

  f32x4 ld0[8], ld1[8], ld2[8], ld3[8];
  LOADX(ld0, wave);
  LOADX(ld1, wave + W);
  LOADX(ld2, wave + 2 * W);
  LOADX(ld3, wave + 3 * W);

  // rolling steady state: wait vmcnt(24), pack, refill, compute
  PACKX(ld0); LOADX(ld0, wave + 4 * W); TILE_COMPUTE();
  PACKX(ld1); LOADX(ld1, wave + 5 * W); TILE_COMPUTE();
  PACKX(ld2); LOADX(ld2, wave + 6 * W); TILE_COMPUTE();
  PACKX(ld3); LOADX(ld3, wave + 7 * W); TILE_COMPUTE();
  // drain
  PACKX(ld0); TILE_COMPUTE();
  PACKX(ld1); TILE_COMPUTE();
  PACKX(ld2); TILE_COMPUTE();
  PACKX(ld3); TILE_COMPUTE();

  // wave reduce -> block reduce -> one plain store per block (no atomic, no
  // ws pre-zero: ws[blockIdx.x] is overwritten before final reads it)
  for (int off = 1; off < 64; off <<= 1) hacc += __shfl_xor(hacc, off, 64);
  __shared__ float red[4];
  if (lane == 0) red[wid] = hacc;
  __syncthreads();
  if (tid == 0) ws[blockIdx.x] = red[0] + red[1] + red[2] + red[3];
}

__global__ void final_kernel(const float* __restrict__ m, const float* ws, float* out,
                             int nRows, int nBlocks) {
  __shared__ float mu[D];
  int lane = threadIdx.x;  // 64 threads
  for (int d = lane; d < D; d += 64) {
    float s = 0.f;
    for (int j = 0; j < K; ++j) s += m[j * D + d];
    mu[d] = s * (1.0f / K);
  }
  __syncthreads();

  // sum per-block partials of the intra entropy
  float part = 0.f;
  for (int i = lane; i < nBlocks; i += 64) part += ws[i];
  for (int off = 1; off < 64; off <<= 1) part += __shfl_xor(part, off, 64);

  const float* mr = m + lane * D;
  float dot = 0.f, nrm = 0.f;
  for (int d = 0; d < D; ++d) {
    dot += mu[d] * mr[d];
    nrm += mr[d] * mr[d];
  }
  float s = 2.f * dot - nrm;  // shift-invariant: drop ||mu||^2
  float mx = s;
  for (int off = 1; off < 64; off <<= 1) mx = fmaxf(mx, __shfl_xor(mx, off, 64));
  float t = s - mx;
  float e = __expf(t);
  float S0 = e, S1 = t * e;
  for (int off = 1; off < 64; off <<= 1) {
    S0 += __shfl_xor(S0, off, 64);
    S1 += __shfl_xor(S1, off, 64);
  }
  float inter = __logf(S0) - S1 / S0;
  if (lane == 0) {
    float intra = part / (float)nRows;
    out[0] = intra - inter;  // LAMB = 1
    out[1] = intra;
    out[2] = inter;
  }
}

extern "C" void kernel_launch(void* const* d_in, const int* in_sizes, int n_in,
                              void* d_out, int out_size, void* d_ws, size_t ws_size,
                              hipStream_t stream) {
  const float* x = (const float*)d_in[0];
  const float* m = (const float*)d_in[1];
  float* ws = (float*)d_ws;
  float* out = (float*)d_out;
  const int N = in_sizes[0] / D;       // 262144

  const int blocks = 512;              // 2 blocks/CU, single fully-resident batch
  const int totalWaves = blocks * 4;   // 2048 waves x exactly 8 tiles = 16384
  main_kernel<<<blocks, 256, 0, stream>>>(x, m, ws, totalWaves);

  final_kernel<<<1, 64, 0, stream>>>(m, ws, out, N, blocks);
}

// Round 7
// 187.326 us; speedup vs baseline: 1.2077x; 1.0579x over previous
//
#include <hip/hip_runtime.h>

#define D 128
#define K 64

typedef __attribute__((ext_vector_type(8))) short short8;   // 8 bf16 in 4 VGPRs
typedef __attribute__((ext_vector_type(2))) int int2v;      // 4 bf16 in 2 VGPRs
typedef __attribute__((ext_vector_type(4))) float f32x4;

// HW packed f32x2 -> bf16x2 (RNE). No builtin on gfx950 -> asm.
__device__ inline int cvt_pk_bf16(float lo, float hi) {
  int r;
  asm("v_cvt_pk_bf16_f32 %0, %1, %2" : "=v"(r) : "v"(lo), "v"(hi));
  return r;
}

// DPP row_ror allreduce (16-lane rows = lid groups). Pure VALU, no DS pipe.
template<int CTRL>
__device__ inline float dpp_ror(float x) {
  return __builtin_bit_cast(float, __builtin_amdgcn_update_dpp(
      0, __builtin_bit_cast(int, x), CTRL, 0xF, 0xF, true));
}
__device__ inline float rowsum16(float v) {
  v += dpp_ror<0x121>(v);
  v += dpp_ror<0x122>(v);
  v += dpp_ror<0x124>(v);
  v += dpp_ror<0x128>(v);
  return v;
}
__device__ inline float rowmax16(float v) {
  v = fmaxf(v, dpp_ror<0x121>(v));
  v = fmaxf(v, dpp_ror<0x122>(v));
  v = fmaxf(v, dpp_ror<0x124>(v));
  v = fmaxf(v, dpp_ror<0x128>(v));
  return v;
}

// Load tile t's 16x128 f32 rows, fully coalesced AND non-temporal: x is
// streamed exactly once, so allocating it in L2/L3 only evicts the fill's
// dirty lines and puts their writeback on our read-critical path. nt loads
// leave the cache alone -> HBM serves pure reads during main.
#define LOADX(dst, t) do {                                                  \
    const f32x4* xb = (const f32x4*)(x + (size_t)(t) * (16 * D)) + lane;    \
    _Pragma("unroll") for (int p = 0; p < 8; ++p)                           \
      dst[p] = __builtin_nontemporal_load(xb + p * 64);                     \
  } while (0)

// Pack f32->bf16 and stage into this wave's LDS tile (row-XOR chunk swizzle).
#define PACKX(src) do {                                                     \
    _Pragma("unroll") for (int p = 0; p < 8; ++p) {                         \
      f32x4 v = src[p];                                                     \
      int2v s;                                                              \
      s[0] = cvt_pk_bf16(v[0], v[1]);                                       \
      s[1] = cvt_pk_bf16(v[2], v[3]);                                       \
      int r = 2 * p + hi;                                                   \
      *(int2v*)(amem + r * 256 + ((wc ^ r) << 4) + wh * 8) = s;             \
    }                                                                       \
  } while (0)

// ds_read A fragments, 16 MFMA, online-entropy epilogue -> hacc.
#define TILE_COMPUTE() do {                                                 \
    f32x4 acc[4];                                                           \
    _Pragma("unroll") for (int jt = 0; jt < 4; ++jt)                        \
      acc[jt] = (f32x4){0.f, 0.f, 0.f, 0.f};                                \
    _Pragma("unroll") for (int kk = 0; kk < 4; ++kk) {                      \
      short8 afrag = *(const short8*)(amem + ra[kk]);                       \
      _Pragma("unroll") for (int jt = 0; jt < 4; ++jt)                      \
        acc[jt] = __builtin_amdgcn_mfma_f32_16x16x32_bf16(                  \
            afrag, bsm[cbase[kk] + jt * 256], acc[jt], 0, 0, 0);            \
    }                                                                       \
    _Pragma("unroll") for (int r = 0; r < 4; ++r) {                         \
      float s0 = acc[0][r] - mn[0];                                         \
      float s1 = acc[1][r] - mn[1];                                         \
      float s2 = acc[2][r] - mn[2];                                         \
      float s3 = acc[3][r] - mn[3];                                         \
      float mx = rowmax16(fmaxf(fmaxf(s0, s1), fmaxf(s2, s3)));             \
      float t0 = s0 - mx, t1 = s1 - mx, t2 = s2 - mx, t3 = s3 - mx;         \
      float e0 = __expf(t0), e1 = __expf(t1);                               \
      float e2 = __expf(t2), e3 = __expf(t3);                               \
      float S0 = rowsum16((e0 + e1) + (e2 + e3));                           \
      float S1 = rowsum16((t0 * e0 + t1 * e1) + (t2 * e2 + t3 * e3));       \
      float H = __logf(S0) - S1 / S0;                                       \
      hacc += (lid == 0) ? H : 0.0f;                                        \
    }                                                                       \
  } while (0)

// Single-batch residency: 512 blocks x 256 thr = 2 blocks/CU, ALL resident.
// 8 tiles/wave, rolling depth-4 pipeline: 24 loads (24 KB) in flight per wave
// continuously, never draining to vmcnt(0) until the final 4 tiles.
__launch_bounds__(256, 2)
__global__ void main_kernel(const float* __restrict__ x, const float* __restrict__ m,
                            float* ws, int totalWaves) {
  __shared__ short8 bsm[1024];        // 16 KB: bf16(2*m), chunk-swizzled
  __shared__ float mnorms[K];
  __shared__ char asmem[4][4096];     // per-wave A staging tiles

  const int tid = threadIdx.x;

  // Block-local prep, vectorized (f32x4). m is 32 KB, L2/L3-served.
  const f32x4* mv4 = (const f32x4*)m;
#pragma unroll
  for (int i0 = 0; i0 < (K * D) / 4; i0 += 256) {
    int i = i0 + tid;
    f32x4 v = mv4[i];
    int c = i >> 1, h = i & 1;          // 16B chunk / half within chunk
    int cs = c ^ ((c >> 4) & 7);        // row-XOR chunk swizzle
    int2v s;
    s[0] = cvt_pk_bf16(2.f * v[0], 2.f * v[1]);
    s[1] = cvt_pk_bf16(2.f * v[2], 2.f * v[3]);
    *(int2v*)((char*)bsm + cs * 16 + h * 8) = s;
  }
  if (tid < K) {
    const f32x4* mr = (const f32x4*)(m + tid * D);
    float s = 0.f;
#pragma unroll
    for (int i = 0; i < 32; ++i) {
      f32x4 v = mr[i];
      s += (v[0] * v[0] + v[1] * v[1]) + (v[2] * v[2] + v[3] * v[3]);
    }
    mnorms[tid] = s;
  }
  __syncthreads();

  const int lane = tid & 63;
  const int lid  = lane & 15;   // A row / B col / C-D col (j)
  const int quad = lane >> 4;   // k group; C/D row = quad*4+reg
  const int wid  = tid >> 6;
  char* amem = asmem[wid];

  float mn[4];
#pragma unroll
  for (int jt = 0; jt < 4; ++jt) mn[jt] = mnorms[jt * 16 + lid];

  int cbase[4], ra[4];
#pragma unroll
  for (int kk = 0; kk < 4; ++kk) {
    cbase[kk] = (lid * 16 + kk * 4 + quad) ^ (lid & 7);
    ra[kk] = lid * 256 + ((((kk << 2) | quad) ^ lid) << 4);
  }

  // A-stage write constants: load p gives lane i floats p*256 + i*4..+3
  //   row r = 2p + (i>>5), chunk c = (i&31)>>1, half h = i&1
  const int hi = lane >> 5;
  const int wc = (lane & 31) >> 1;
  const int wh = lane & 1;

  const int wave = blockIdx.x * 4 + wid;
  const int W = totalWaves;           // 2048: tiles wave + k*W, k = 0..7 exact
  float hacc = 0.f;

  f32x4 ld0[8], ld1[8], ld2[8], ld3[8];
  LOADX(ld0, wave);
  LOADX(ld1, wave + W);
  LOADX(ld2, wave + 2 * W);
  LOADX(ld3, wave + 3 * W);

  // rolling steady state: wait vmcnt(24), pack, refill, compute
  PACKX(ld0); LOADX(ld0, wave + 4 * W); TILE_COMPUTE();
  PACKX(ld1); LOADX(ld1, wave + 5 * W); TILE_COMPUTE();
  PACKX(ld2); LOADX(ld2, wave + 6 * W); TILE_COMPUTE();
  PACKX(ld3); LOADX(ld3, wave + 7 * W); TILE_COMPUTE();
  // drain
  PACKX(ld0); TILE_COMPUTE();
  PACKX(ld1); TILE_COMPUTE();
  PACKX(ld2); TILE_COMPUTE();
  PACKX(ld3); TILE_COMPUTE();

  // wave reduce -> block reduce -> one plain store per block (no atomic, no
  // ws pre-zero: ws[blockIdx.x] is overwritten before final reads it)
  for (int off = 1; off < 64; off <<= 1) hacc += __shfl_xor(hacc, off, 64);
  __shared__ float red[4];
  if (lane == 0) red[wid] = hacc;
  __syncthreads();
  if (tid == 0) ws[blockIdx.x] = red[0] + red[1] + red[2] + red[3];
}

__global__ void final_kernel(const float* __restrict__ m, const float* ws, float* out,
                             int nRows, int nBlocks) {
  __shared__ float mu[D];
  int lane = threadIdx.x;  // 64 threads
  for (int d = lane; d < D; d += 64) {
    float s = 0.f;
    for (int j = 0; j < K; ++j) s += m[j * D + d];
    mu[d] = s * (1.0f / K);
  }
  __syncthreads();

  // sum per-block partials of the intra entropy
  float part = 0.f;
  for (int i = lane; i < nBlocks; i += 64) part += ws[i];
  for (int off = 1; off < 64; off <<= 1) part += __shfl_xor(part, off, 64);

  const float* mr = m + lane * D;
  float dot = 0.f, nrm = 0.f;
  for (int d = 0; d < D; ++d) {
    dot += mu[d] * mr[d];
    nrm += mr[d] * mr[d];
  }
  float s = 2.f * dot - nrm;  // shift-invariant: drop ||mu||^2
  float mx = s;
  for (int off = 1; off < 64; off <<= 1) mx = fmaxf(mx, __shfl_xor(mx, off, 64));
  float t = s - mx;
  float e = __expf(t);
  float S0 = e, S1 = t * e;
  for (int off = 1; off < 64; off <<= 1) {
    S0 += __shfl_xor(S0, off, 64);
    S1 += __shfl_xor(S1, off, 64);
  }
  float inter = __logf(S0) - S1 / S0;
  if (lane == 0) {
    float intra = part / (float)nRows;
    out[0] = intra - inter;  // LAMB = 1
    out[1] = intra;
    out[2] = inter;
  }
}

extern "C" void kernel_launch(void* const* d_in, const int* in_sizes, int n_in,
                              void* d_out, int out_size, void* d_ws, size_t ws_size,
                              hipStream_t stream) {
  const float* x = (const float*)d_in[0];
  const float* m = (const float*)d_in[1];
  float* ws = (float*)d_ws;
  float* out = (float*)d_out;
  const int N = in_sizes[0] / D;       // 262144

  const int blocks = 512;              // 2 blocks/CU, single fully-resident batch
  const int totalWaves = blocks * 4;   // 2048 waves x exactly 8 tiles = 16384
  main_kernel<<<blocks, 256, 0, stream>>>(x, m, ws, totalWaves);

  final_kernel<<<1, 64, 0, stream>>>(m, ws, out, N, blocks);
}